// Round 3
// baseline (340.772 us; speedup 1.0000x reference)
//
#include <hip/hip_runtime.h>
#include <math.h>

#define DEV __device__ __forceinline__
DEV float leakyf(float v) { return v >= 0.f ? v : 0.01f * v; }
DEV int rfl(int v) { return __builtin_amdgcn_readfirstlane(v); }

// ---- ws layout (float offsets) ----
#define OFF_A    0u          // h1  [64][8][64][64]   2097152
#define OFF_B    2097152u    // h2  [64][16][32][32]  1048576
#define OFF_C    3145728u    // h3  [64][16][32][32]  1048576
#define OFF_D1   4194304u    // d1  [64][16][32][32]  1048576
#define OFF_D2   5242880u    // dt2 [64][8][64][64]   2097152
#define OFF_IDX  7340032u    // 65536 int32
#define OFF_W1T  7405568u    // 128   [tap16][co8]
#define OFF_W2T  7405696u    // 2048  [cg4][ci8][tap16][co4]
#define OFF_W3T  7407744u    // 2304  [cg4][ci16][tap9][co4]
#define OFF_W4T  7410048u    // 1024  [ci16][d64]
#define OFF_WT2T 7411072u    // 2048  [cg2][ci16][tap16][co4]
#define OFF_C2   7413120u    // 512
#define OFF_U    7413632u    // 73728 [k512][tap9][co16]
#define OFF_LOSS 7487360u    // 1

// ---------- prep: weight transposes + |c|^2 ----------
__global__ void prep_k(const float* __restrict__ ew1, const float* __restrict__ ew2,
                       const float* __restrict__ ew3, const float* __restrict__ ew4,
                       const float* __restrict__ dw2, const float* __restrict__ cb,
                       float* __restrict__ ws)
{
    int b = blockIdx.x, t = threadIdx.x;
    if (b < 8) {                      // W2T: [((cg*8+ci)*16+tap)*4+cj] = ew2[co][ci][tap]
        int id = b * 256 + t;
        int cj = id & 3, tap = (id >> 2) & 15, ci = (id >> 6) & 7, cg = id >> 9;
        ws[OFF_W2T + id] = ew2[(((cg * 4 + cj) * 8) + ci) * 16 + tap];
    } else if (b < 17) {              // W3T: [((cg*16+ci)*9+tap)*4+cj]
        int id = (b - 8) * 256 + t;
        if (id < 2304) {
            int cj = id & 3, r = id >> 2;
            int tap = r % 9, ci = (r / 9) & 15, cg = r / 144;
            ws[OFF_W3T + id] = ew3[(((cg * 4 + cj) * 16) + ci) * 9 + tap];
        }
    } else if (b < 21) {              // W4T: [ci*64+d] = ew4[d][ci]
        int id = (b - 17) * 256 + t;
        int d = id & 63, ci = id >> 6;
        ws[OFF_W4T + id] = ew4[d * 16 + ci];
    } else if (b < 29) {              // WT2T: [((cg*16+ci)*16+tap)*4+cj] = dw2[ci][co][tap]
        int id = (b - 21) * 256 + t;
        int cj = id & 3, tap = (id >> 2) & 15, ci = (id >> 6) & 15, cg = id >> 10;
        ws[OFF_WT2T + id] = dw2[((ci * 8) + cg * 4 + cj) * 16 + tap];
    } else if (b == 29) {             // W1T: [tap*8+co] = ew1[co][tap]
        if (t < 128) {
            int co = t & 7, tap = t >> 3;
            ws[OFF_W1T + t] = ew1[co * 16 + tap];
        }
    } else {                          // C2
        int k = (b - 30) * 256 + t;
        float s = 0.f;
        #pragma unroll
        for (int d = 0; d < 64; ++d) { float v = cb[k * 64 + d]; s = fmaf(v, v, s); }
        ws[OFF_C2 + k] = s;
    }
}

// U[k][tap][co] = sum_ci dw1[co][ci][tap] * cb[k][ci]
__global__ void uprep_k(const float* __restrict__ dw1, const float* __restrict__ cb,
                        float* __restrict__ U)
{
    int id = blockIdx.x * 256 + threadIdx.x;   // 73728
    int co = id & 15, r = id >> 4;
    int tap = r % 9, k = r / 9;
    float s = 0.f;
    #pragma unroll
    for (int ci = 0; ci < 64; ++ci)
        s = fmaf(cb[k * 64 + ci], dw1[(co * 64 + ci) * 9 + tap], s);
    U[id] = s;
}

// ---------- encoder ----------
__global__ __launch_bounds__(256) void e1_k(const float* __restrict__ x,
                                            const float* __restrict__ w1t,
                                            const float* __restrict__ eb1,
                                            float* __restrict__ out)
{
    int id = blockIdx.x * 256 + threadIdx.x;          // 262144
    int px = id & 63, py = (id >> 6) & 63, n = id >> 12;
    float acc[8];
    #pragma unroll
    for (int j = 0; j < 8; ++j) acc[j] = eb1[j];
    const float4* w4p = (const float4*)w1t;
    const float* ip = x + (n << 14);
    #pragma unroll
    for (int ky = 0; ky < 4; ++ky) {
        int iy = 2 * py - 1 + ky;
        bool vy = iy >= 0 && iy < 128;
        #pragma unroll
        for (int kx = 0; kx < 4; ++kx) {
            int ix = 2 * px - 1 + kx;
            float v = (vy && ix >= 0 && ix < 128) ? ip[(iy << 7) + ix] : 0.f;
            float4 wa = w4p[(ky * 4 + kx) * 2], wb = w4p[(ky * 4 + kx) * 2 + 1];
            acc[0] = fmaf(v, wa.x, acc[0]); acc[1] = fmaf(v, wa.y, acc[1]);
            acc[2] = fmaf(v, wa.z, acc[2]); acc[3] = fmaf(v, wa.w, acc[3]);
            acc[4] = fmaf(v, wb.x, acc[4]); acc[5] = fmaf(v, wb.y, acc[5]);
            acc[6] = fmaf(v, wb.z, acc[6]); acc[7] = fmaf(v, wb.w, acc[7]);
        }
    }
    #pragma unroll
    for (int j = 0; j < 8; ++j)
        out[((n * 8 + j) << 12) + (py << 6) + px] = leakyf(acc[j]);
}

__global__ __launch_bounds__(256) void e2_k(const float* __restrict__ in,
                                            const float* __restrict__ w2t,
                                            const float* __restrict__ eb2,
                                            float* __restrict__ out)
{
    int id = blockIdx.x * 256 + threadIdx.x;          // 262144
    int x = id & 31, y = (id >> 5) & 31;
    int cg = rfl((id >> 10) & 3), n = id >> 12;
    float acc[4];
    #pragma unroll
    for (int j = 0; j < 4; ++j) acc[j] = eb2[cg * 4 + j];
    const float4* w4p = (const float4*)w2t;
    #pragma unroll
    for (int ci = 0; ci < 8; ++ci) {
        const float* ip = in + ((n * 8 + ci) << 12);
        #pragma unroll
        for (int ky = 0; ky < 4; ++ky) {
            int iy = 2 * y - 1 + ky;
            bool vy = iy >= 0 && iy < 64;
            #pragma unroll
            for (int kx = 0; kx < 4; ++kx) {
                int ix = 2 * x - 1 + kx;
                float v = (vy && ix >= 0 && ix < 64) ? ip[(iy << 6) + ix] : 0.f;
                float4 wv = w4p[(cg * 8 + ci) * 16 + ky * 4 + kx];
                acc[0] = fmaf(v, wv.x, acc[0]); acc[1] = fmaf(v, wv.y, acc[1]);
                acc[2] = fmaf(v, wv.z, acc[2]); acc[3] = fmaf(v, wv.w, acc[3]);
            }
        }
    }
    #pragma unroll
    for (int j = 0; j < 4; ++j)
        out[((n * 16 + cg * 4 + j) << 10) + (y << 5) + x] = leakyf(acc[j]);
}

__global__ __launch_bounds__(256) void e3_k(const float* __restrict__ in,
                                            const float* __restrict__ w3t,
                                            const float* __restrict__ eb3,
                                            float* __restrict__ out)
{
    int id = blockIdx.x * 256 + threadIdx.x;          // 262144
    int x = id & 31, y = (id >> 5) & 31;
    int cg = rfl((id >> 10) & 3), n = id >> 12;
    float acc[4];
    #pragma unroll
    for (int j = 0; j < 4; ++j) acc[j] = eb3[cg * 4 + j];
    const float4* w4p = (const float4*)w3t;
    #pragma unroll
    for (int ci = 0; ci < 16; ++ci) {
        const float* ip = in + ((n * 16 + ci) << 10);
        #pragma unroll
        for (int tap = 0; tap < 9; ++tap) {
            int iy = y + tap / 3 - 1, ix = x + tap % 3 - 1;
            float v = (iy >= 0 && iy < 32 && ix >= 0 && ix < 32) ? ip[(iy << 5) + ix] : 0.f;
            float4 wv = w4p[(cg * 16 + ci) * 9 + tap];
            acc[0] = fmaf(v, wv.x, acc[0]); acc[1] = fmaf(v, wv.y, acc[1]);
            acc[2] = fmaf(v, wv.z, acc[2]); acc[3] = fmaf(v, wv.w, acc[3]);
        }
    }
    #pragma unroll
    for (int j = 0; j < 4; ++j)
        out[((n * 16 + cg * 4 + j) << 10) + (y << 5) + x] = leakyf(acc[j]);
}

// ---------- fused e4 (1x1 conv) + VQ argmin + loss, outputs indices ----------
__global__ __launch_bounds__(256) void vq3_k(const float* __restrict__ h3,
                                             const float* __restrict__ cb,
                                             const float* __restrict__ w4t,
                                             const float* __restrict__ c2,
                                             const float* __restrict__ eb4,
                                             int* __restrict__ idxOut,
                                             float* __restrict__ lossAcc)
{
    __shared__ float sS[256];
    __shared__ int   sI[256];
    int t = threadIdx.x, lane = t & 63;
    int w = rfl(t >> 6);
    int m = blockIdx.x * 64 + lane;
    int n = m >> 10, pos = m & 1023;

    // e4: f = leaky(W4 h3 + b4), SGPR-streamed weights
    const float* hp = h3 + (n << 14) + pos;
    float h[16];
    #pragma unroll
    for (int ci = 0; ci < 16; ++ci) h[ci] = hp[ci << 10];
    float f[64];
    #pragma unroll
    for (int d = 0; d < 64; ++d) f[d] = eb4[d];
    #pragma unroll
    for (int ci = 0; ci < 16; ++ci) {
        float v = h[ci];
        #pragma unroll
        for (int d = 0; d < 64; ++d) f[d] = fmaf(v, w4t[ci * 64 + d], f[d]);
    }
    #pragma unroll
    for (int d = 0; d < 64; ++d) f[d] = leakyf(f[d]);

    // this wave scans codes [w*128, w*128+128)
    const float4* cb4 = (const float4*)cb;
    int k0 = w << 7;
    float best = 3.4e38f; int bk = 0;
    #pragma unroll 1
    for (int kk = 0; kk < 128; kk += 2) {
        int ka = k0 + kk, kb = ka + 1;
        float a0 = 0.f, a1 = 0.f, a2 = 0.f, a3 = 0.f;
        float b0 = 0.f, b1 = 0.f, b2 = 0.f, b3 = 0.f;
        #pragma unroll
        for (int q = 0; q < 16; ++q) {
            float4 ca = cb4[ka * 16 + q];
            float4 cbv = cb4[kb * 16 + q];
            a0 = fmaf(f[q * 4 + 0], ca.x, a0);
            a1 = fmaf(f[q * 4 + 1], ca.y, a1);
            a2 = fmaf(f[q * 4 + 2], ca.z, a2);
            a3 = fmaf(f[q * 4 + 3], ca.w, a3);
            b0 = fmaf(f[q * 4 + 0], cbv.x, b0);
            b1 = fmaf(f[q * 4 + 1], cbv.y, b1);
            b2 = fmaf(f[q * 4 + 2], cbv.z, b2);
            b3 = fmaf(f[q * 4 + 3], cbv.w, b3);
        }
        float sa = fmaf(0.5f, c2[ka], -((a0 + a1) + (a2 + a3)));
        float sb = fmaf(0.5f, c2[kb], -((b0 + b1) + (b2 + b3)));
        if (sa < best) { best = sa; bk = ka; }
        if (sb < best) { best = sb; bk = kb; }
    }
    sS[t] = best; sI[t] = bk;
    __syncthreads();
    if (t < 64) {
        float bs = sS[t]; int bi = sI[t];
        #pragma unroll
        for (int ww = 1; ww < 4; ++ww) {       // ascending k ranges: strict < keeps first min
            float s2 = sS[ww * 64 + t];
            int   i2 = sI[ww * 64 + t];
            if (s2 < bs) { bs = s2; bi = i2; }
        }
        idxOut[blockIdx.x * 64 + t] = bi;
        // loss: sum (cb[bi] - f)^2  (commitment == embedding in fwd)
        float rs = 0.f;
        #pragma unroll
        for (int q = 0; q < 16; ++q) {
            float4 c = cb4[bi * 16 + q];
            float d0 = c.x - f[q * 4 + 0], d1 = c.y - f[q * 4 + 1];
            float d2 = c.z - f[q * 4 + 2], d3 = c.w - f[q * 4 + 3];
            rs = fmaf(d0, d0, rs); rs = fmaf(d1, d1, rs);
            rs = fmaf(d2, d2, rs); rs = fmaf(d3, d3, rs);
        }
        #pragma unroll
        for (int off = 32; off; off >>= 1) rs += __shfl_down(rs, off, 64);
        if (t == 0) atomicAdd(lossAcc, rs);
    }
}

// ---------- decoder conv1 via U-table ----------
__global__ __launch_bounds__(256) void d1_k(const int* __restrict__ idx,
                                            const float* __restrict__ U,
                                            const float* __restrict__ db1,
                                            float* __restrict__ out)
{
    int id = blockIdx.x * 256 + threadIdx.x;          // 131072
    int x = id & 31, y = (id >> 5) & 31;
    int cg = rfl((id >> 10) & 1), n = id >> 11;
    float acc[8];
    #pragma unroll
    for (int j = 0; j < 8; ++j) acc[j] = db1[cg * 8 + j];
    const float4* U4 = (const float4*)U;
    #pragma unroll
    for (int tap = 0; tap < 9; ++tap) {
        int yy = y + tap / 3 - 1, xx = x + tap % 3 - 1;
        if (yy < 0 || yy > 31 || xx < 0 || xx > 31) continue;
        int k = idx[(n << 10) + (yy << 5) + xx];
        int base = ((k * 9 + tap) * 16 + cg * 8) >> 2;
        float4 u0 = U4[base], u1 = U4[base + 1];
        acc[0] += u0.x; acc[1] += u0.y; acc[2] += u0.z; acc[3] += u0.w;
        acc[4] += u1.x; acc[5] += u1.y; acc[6] += u1.z; acc[7] += u1.w;
    }
    #pragma unroll
    for (int j = 0; j < 8; ++j)
        out[((n * 16 + cg * 8 + j) << 10) + (y << 5) + x] = leakyf(acc[j]);
}

// ---------- ConvT 16->8, K4 S2 P1, parity-block form ----------
__global__ __launch_bounds__(256) void dt2_k(const float* __restrict__ in,
                                             const float* __restrict__ wt,
                                             const float* __restrict__ db2,
                                             float* __restrict__ out)
{
    int id = blockIdx.x * 256 + threadIdx.x;          // 131072
    int x = id & 31, y = (id >> 5) & 31;
    int cg = rfl((id >> 10) & 1), n = id >> 11;
    float acc[2][2][4];
    #pragma unroll
    for (int py = 0; py < 2; ++py)
        #pragma unroll
        for (int px = 0; px < 2; ++px)
            #pragma unroll
            for (int j = 0; j < 4; ++j) acc[py][px][j] = db2[cg * 4 + j];
    const float4* wt4 = (const float4*)wt;
    #pragma unroll
    for (int ci = 0; ci < 16; ++ci) {
        const float* ip = in + ((n * 16 + ci) << 10);
        float v[3][3];
        #pragma unroll
        for (int dy = -1; dy <= 1; ++dy)
            #pragma unroll
            for (int dx = -1; dx <= 1; ++dx) {
                int yy = y + dy, xx = x + dx;
                v[dy + 1][dx + 1] = (yy >= 0 && yy < 32 && xx >= 0 && xx < 32)
                                        ? ip[(yy << 5) + xx] : 0.f;
            }
        #pragma unroll
        for (int ky = 0; ky < 4; ++ky) {
            int py = (ky + 1) & 1;
            int dy = (ky == 0) ? 1 : (ky == 3 ? -1 : 0);
            #pragma unroll
            for (int kx = 0; kx < 4; ++kx) {
                int px = (kx + 1) & 1;
                int dx = (kx == 0) ? 1 : (kx == 3 ? -1 : 0);
                float4 wv = wt4[(cg * 16 + ci) * 16 + ky * 4 + kx];
                float vv = v[dy + 1][dx + 1];
                acc[py][px][0] = fmaf(vv, wv.x, acc[py][px][0]);
                acc[py][px][1] = fmaf(vv, wv.y, acc[py][px][1]);
                acc[py][px][2] = fmaf(vv, wv.z, acc[py][px][2]);
                acc[py][px][3] = fmaf(vv, wv.w, acc[py][px][3]);
            }
        }
    }
    #pragma unroll
    for (int py = 0; py < 2; ++py)
        #pragma unroll
        for (int px = 0; px < 2; ++px)
            #pragma unroll
            for (int j = 0; j < 4; ++j)
                out[((n * 8 + cg * 4 + j) << 12) + ((2 * y + py) << 6) + 2 * x + px] =
                    leakyf(acc[py][px][j]);
}

// ---------- ConvT 8->1, K4 S2 P1, tanh ----------
__global__ __launch_bounds__(256) void dt3_k(const float* __restrict__ in,
                                             const float* __restrict__ dw3,
                                             const float* __restrict__ db3,
                                             float* __restrict__ out)
{
    int id = blockIdx.x * 256 + threadIdx.x;          // 262144
    int x = id & 63, y = (id >> 6) & 63, n = id >> 12;
    float b = db3[0];
    float acc[2][2] = {{b, b}, {b, b}};
    #pragma unroll
    for (int ci = 0; ci < 8; ++ci) {
        const float* ip = in + ((n * 8 + ci) << 12);
        float v[3][3];
        #pragma unroll
        for (int dy = -1; dy <= 1; ++dy)
            #pragma unroll
            for (int dx = -1; dx <= 1; ++dx) {
                int yy = y + dy, xx = x + dx;
                v[dy + 1][dx + 1] = (yy >= 0 && yy < 64 && xx >= 0 && xx < 64)
                                        ? ip[(yy << 6) + xx] : 0.f;
            }
        #pragma unroll
        for (int ky = 0; ky < 4; ++ky) {
            int py = (ky + 1) & 1;
            int dy = (ky == 0) ? 1 : (ky == 3 ? -1 : 0);
            #pragma unroll
            for (int kx = 0; kx < 4; ++kx) {
                int px = (kx + 1) & 1;
                int dx = (kx == 0) ? 1 : (kx == 3 ? -1 : 0);
                acc[py][px] = fmaf(v[dy + 1][dx + 1], dw3[ci * 16 + ky * 4 + kx], acc[py][px]);
            }
        }
    }
    #pragma unroll
    for (int py = 0; py < 2; ++py)
        #pragma unroll
        for (int px = 0; px < 2; ++px)
            out[(n << 14) + ((2 * y + py) << 7) + 2 * x + px] = tanhf(acc[py][px]);
}

__global__ void loss_k(const float* __restrict__ acc, float* __restrict__ out)
{
    out[0] = 1.25f * acc[0] / 4194304.0f;
}

extern "C" void kernel_launch(void* const* d_in, const int* in_sizes, int n_in,
                              void* d_out, int out_size, void* d_ws, size_t ws_size,
                              hipStream_t stream)
{
    const float* x        = (const float*)d_in[0];
    const float* ew1      = (const float*)d_in[1];
    const float* eb1      = (const float*)d_in[2];
    const float* ew2      = (const float*)d_in[3];
    const float* eb2      = (const float*)d_in[4];
    const float* ew3      = (const float*)d_in[5];
    const float* eb3      = (const float*)d_in[6];
    const float* ew4      = (const float*)d_in[7];
    const float* eb4      = (const float*)d_in[8];
    const float* codebook = (const float*)d_in[9];
    const float* dw1      = (const float*)d_in[10];
    const float* db1      = (const float*)d_in[11];
    const float* dw2      = (const float*)d_in[12];
    const float* db2      = (const float*)d_in[13];
    const float* dw3      = (const float*)d_in[14];
    const float* db3      = (const float*)d_in[15];

    float* out = (float*)d_out;
    float* ws  = (float*)d_ws;
    float* A    = ws + OFF_A;
    float* B    = ws + OFF_B;
    float* C    = ws + OFF_C;
    float* D1   = ws + OFF_D1;
    float* D2   = ws + OFF_D2;
    int*   IDX  = (int*)(ws + OFF_IDX);
    float* W1T  = ws + OFF_W1T;
    float* W2T  = ws + OFF_W2T;
    float* W3T  = ws + OFF_W3T;
    float* W4T  = ws + OFF_W4T;
    float* WT2T = ws + OFF_WT2T;
    float* C2   = ws + OFF_C2;
    float* U    = ws + OFF_U;
    float* LOSS = ws + OFF_LOSS;

    hipMemsetAsync(LOSS, 0, sizeof(float), stream);
    prep_k<<<32, 256, 0, stream>>>(ew1, ew2, ew3, ew4, dw2, codebook, ws);
    uprep_k<<<288, 256, 0, stream>>>(dw1, codebook, U);

    e1_k<<<1024, 256, 0, stream>>>(x, W1T, eb1, A);
    e2_k<<<1024, 256, 0, stream>>>(A, W2T, eb2, B);
    e3_k<<<1024, 256, 0, stream>>>(B, W3T, eb3, C);

    vq3_k<<<1024, 256, 0, stream>>>(C, codebook, W4T, C2, eb4, IDX, LOSS);

    d1_k<<<512, 256, 0, stream>>>(IDX, U, db1, D1);
    dt2_k<<<512, 256, 0, stream>>>(D1, WT2T, db2, D2);
    dt3_k<<<1024, 256, 0, stream>>>(D2, dw3, db3, out);

    loss_k<<<1, 1, 0, stream>>>(LOSS, out + 1048576);
}

// Round 4
// 333.604 us; speedup vs baseline: 1.0215x; 1.0215x over previous
//
#include <hip/hip_runtime.h>
#include <math.h>

#define DEV __device__ __forceinline__
DEV float leakyf(float v) { return v >= 0.f ? v : 0.01f * v; }
DEV int rfl(int v) { return __builtin_amdgcn_readfirstlane(v); }

// ---- ws layout (float offsets) ----
#define OFF_A    0u          // h1  [64][8][64][64]   2097152
#define OFF_B    2097152u    // h2  [64][16][32][32]  1048576
#define OFF_C    3145728u    // h3  [64][16][32][32]  1048576
#define OFF_D1   4194304u    // d1  [64][16][32][32]  1048576
#define OFF_D2   5242880u    // dt2 [64][8][64][64]   2097152
#define OFF_IDX  7340032u    // 65536 int32
#define OFF_W1T  7405568u    // 128   [tap16][co8]
#define OFF_W2T  7405696u    // 2048  [cg4][ci8][tap16][co4]
#define OFF_W3T  7407744u    // 2304  [cg4][ci16][tap9][co4]
#define OFF_W4T  7410048u    // 1024  [ci16][d64]
#define OFF_WT2T 7411072u    // 2048  [cg2][ci16][tap16][co4]
#define OFF_C2   7413120u    // 512
#define OFF_U    7413632u    // 73728 [k512][tap9][co16]
#define OFF_LOSS 7487360u    // 1 (+pad)
#define OFF_DWT  7487488u    // 9216  [ci64][tap9*16+co16]

// ---------- prep: weight transposes + |c|^2 ----------
__global__ void prep_k(const float* __restrict__ ew1, const float* __restrict__ ew2,
                       const float* __restrict__ ew3, const float* __restrict__ ew4,
                       const float* __restrict__ dw1, const float* __restrict__ dw2,
                       const float* __restrict__ cb, float* __restrict__ ws)
{
    int b = blockIdx.x, t = threadIdx.x;
    if (b < 8) {                      // W2T: [((cg*8+ci)*16+tap)*4+cj] = ew2[co][ci][tap]
        int id = b * 256 + t;
        int cj = id & 3, tap = (id >> 2) & 15, ci = (id >> 6) & 7, cg = id >> 9;
        ws[OFF_W2T + id] = ew2[(((cg * 4 + cj) * 8) + ci) * 16 + tap];
    } else if (b < 17) {              // W3T: [((cg*16+ci)*9+tap)*4+cj]
        int id = (b - 8) * 256 + t;
        if (id < 2304) {
            int cj = id & 3, r = id >> 2;
            int tap = r % 9, ci = (r / 9) & 15, cg = r / 144;
            ws[OFF_W3T + id] = ew3[(((cg * 4 + cj) * 16) + ci) * 9 + tap];
        }
    } else if (b < 21) {              // W4T: [ci*64+d] = ew4[d][ci]
        int id = (b - 17) * 256 + t;
        int d = id & 63, ci = id >> 6;
        ws[OFF_W4T + id] = ew4[d * 16 + ci];
    } else if (b < 29) {              // WT2T: [((cg*16+ci)*16+tap)*4+cj] = dw2[ci][co][tap]
        int id = (b - 21) * 256 + t;
        int cj = id & 3, tap = (id >> 2) & 15, ci = (id >> 6) & 15, cg = id >> 10;
        ws[OFF_WT2T + id] = dw2[((ci * 8) + cg * 4 + cj) * 16 + tap];
    } else if (b == 29) {             // W1T: [tap*8+co] = ew1[co][tap]
        if (t < 128) {
            int co = t & 7, tap = t >> 3;
            ws[OFF_W1T + t] = ew1[co * 16 + tap];
        }
    } else if (b < 32) {              // C2
        int k = (b - 30) * 256 + t;
        float s = 0.f;
        #pragma unroll
        for (int d = 0; d < 64; ++d) { float v = cb[k * 64 + d]; s = fmaf(v, v, s); }
        ws[OFF_C2 + k] = s;
    } else {                          // DWT: [ci*144 + tap*16 + co] = dw1[co][ci][tap]
        int id = (b - 32) * 256 + t;
        if (id < 9216) {
            int co = id & 15, tap = (id >> 4) % 9, ci = id / 144;
            ws[OFF_DWT + id] = dw1[(co * 64 + ci) * 9 + tap];
        }
    }
}

// U[k][tap][co] = sum_ci dwT[ci][tap*16+co] * cb[k][ci]   (coalesced)
__global__ void uprep_k(const float* __restrict__ dwT, const float* __restrict__ cb,
                        float* __restrict__ U)
{
    int id = blockIdx.x * 256 + threadIdx.x;   // 73728 = k*144 + (tap*16+co)
    int k = id / 144;
    int r = id - k * 144;
    float s = 0.f;
    #pragma unroll
    for (int ci = 0; ci < 64; ++ci)
        s = fmaf(cb[k * 64 + ci], dwT[ci * 144 + r], s);
    U[id] = s;
}

// ---------- encoder ----------
__global__ __launch_bounds__(256) void e1_k(const float* __restrict__ x,
                                            const float* __restrict__ w1t,
                                            const float* __restrict__ eb1,
                                            float* __restrict__ out)
{
    int id = blockIdx.x * 256 + threadIdx.x;          // 262144
    int px = id & 63, py = (id >> 6) & 63, n = id >> 12;
    float acc[8];
    #pragma unroll
    for (int j = 0; j < 8; ++j) acc[j] = eb1[j];
    const float4* w4p = (const float4*)w1t;
    const float* ip = x + (n << 14);
    #pragma unroll
    for (int ky = 0; ky < 4; ++ky) {
        int iy = 2 * py - 1 + ky;
        bool vy = iy >= 0 && iy < 128;
        #pragma unroll
        for (int kx = 0; kx < 4; ++kx) {
            int ix = 2 * px - 1 + kx;
            float v = (vy && ix >= 0 && ix < 128) ? ip[(iy << 7) + ix] : 0.f;
            float4 wa = w4p[(ky * 4 + kx) * 2], wb = w4p[(ky * 4 + kx) * 2 + 1];
            acc[0] = fmaf(v, wa.x, acc[0]); acc[1] = fmaf(v, wa.y, acc[1]);
            acc[2] = fmaf(v, wa.z, acc[2]); acc[3] = fmaf(v, wa.w, acc[3]);
            acc[4] = fmaf(v, wb.x, acc[4]); acc[5] = fmaf(v, wb.y, acc[5]);
            acc[6] = fmaf(v, wb.z, acc[6]); acc[7] = fmaf(v, wb.w, acc[7]);
        }
    }
    #pragma unroll
    for (int j = 0; j < 8; ++j)
        out[((n * 8 + j) << 12) + (py << 6) + px] = leakyf(acc[j]);
}

__global__ __launch_bounds__(256) void e2_k(const float* __restrict__ in,
                                            const float* __restrict__ w2t,
                                            const float* __restrict__ eb2,
                                            float* __restrict__ out)
{
    int id = blockIdx.x * 256 + threadIdx.x;          // 262144
    int x = id & 31, y = (id >> 5) & 31;
    int cg = rfl((id >> 10) & 3), n = id >> 12;
    float acc[4];
    #pragma unroll
    for (int j = 0; j < 4; ++j) acc[j] = eb2[cg * 4 + j];
    const float4* w4p = (const float4*)w2t;
    #pragma unroll
    for (int ci = 0; ci < 8; ++ci) {
        const float* ip = in + ((n * 8 + ci) << 12);
        #pragma unroll
        for (int ky = 0; ky < 4; ++ky) {
            int iy = 2 * y - 1 + ky;
            bool vy = iy >= 0 && iy < 64;
            #pragma unroll
            for (int kx = 0; kx < 4; ++kx) {
                int ix = 2 * x - 1 + kx;
                float v = (vy && ix >= 0 && ix < 64) ? ip[(iy << 6) + ix] : 0.f;
                float4 wv = w4p[(cg * 8 + ci) * 16 + ky * 4 + kx];
                acc[0] = fmaf(v, wv.x, acc[0]); acc[1] = fmaf(v, wv.y, acc[1]);
                acc[2] = fmaf(v, wv.z, acc[2]); acc[3] = fmaf(v, wv.w, acc[3]);
            }
        }
    }
    #pragma unroll
    for (int j = 0; j < 4; ++j)
        out[((n * 16 + cg * 4 + j) << 10) + (y << 5) + x] = leakyf(acc[j]);
}

__global__ __launch_bounds__(256) void e3_k(const float* __restrict__ in,
                                            const float* __restrict__ w3t,
                                            const float* __restrict__ eb3,
                                            float* __restrict__ out)
{
    int id = blockIdx.x * 256 + threadIdx.x;          // 262144
    int x = id & 31, y = (id >> 5) & 31;
    int cg = rfl((id >> 10) & 3), n = id >> 12;
    float acc[4];
    #pragma unroll
    for (int j = 0; j < 4; ++j) acc[j] = eb3[cg * 4 + j];
    const float4* w4p = (const float4*)w3t;
    #pragma unroll
    for (int ci = 0; ci < 16; ++ci) {
        const float* ip = in + ((n * 16 + ci) << 10);
        #pragma unroll
        for (int tap = 0; tap < 9; ++tap) {
            int iy = y + tap / 3 - 1, ix = x + tap % 3 - 1;
            float v = (iy >= 0 && iy < 32 && ix >= 0 && ix < 32) ? ip[(iy << 5) + ix] : 0.f;
            float4 wv = w4p[(cg * 16 + ci) * 9 + tap];
            acc[0] = fmaf(v, wv.x, acc[0]); acc[1] = fmaf(v, wv.y, acc[1]);
            acc[2] = fmaf(v, wv.z, acc[2]); acc[3] = fmaf(v, wv.w, acc[3]);
        }
    }
    #pragma unroll
    for (int j = 0; j < 4; ++j)
        out[((n * 16 + cg * 4 + j) << 10) + (y << 5) + x] = leakyf(acc[j]);
}

// ---------- fused e4 (1x1 conv) + VQ argmin + loss, outputs indices ----------
// launch_bounds(256,4): VGPR cap 128 so f[64] + 16 acc chains stay in registers.
__global__ __launch_bounds__(256, 4) void vq3_k(const float* __restrict__ h3,
                                                const float* __restrict__ cb,
                                                const float* __restrict__ w4t,
                                                const float* __restrict__ c2,
                                                const float* __restrict__ eb4,
                                                int* __restrict__ idxOut,
                                                float* __restrict__ lossAcc)
{
    __shared__ float sS[256];
    __shared__ int   sI[256];
    int t = threadIdx.x, lane = t & 63;
    int w = rfl(t >> 6);
    int m = blockIdx.x * 64 + lane;
    int n = m >> 10, pos = m & 1023;

    // e4: f = leaky(W4 h3 + b4), SGPR-streamed weights
    const float* hp = h3 + (n << 14) + pos;
    float h[16];
    #pragma unroll
    for (int ci = 0; ci < 16; ++ci) h[ci] = hp[ci << 10];
    float f[64];
    #pragma unroll
    for (int d = 0; d < 64; ++d) f[d] = eb4[d];
    #pragma unroll
    for (int ci = 0; ci < 16; ++ci) {
        float v = h[ci];
        #pragma unroll
        for (int d = 0; d < 64; ++d) f[d] = fmaf(v, w4t[ci * 64 + d], f[d]);
    }
    #pragma unroll
    for (int d = 0; d < 64; ++d) f[d] = leakyf(f[d]);

    // this wave scans codes [w*128, w*128+128), 4 codes per iter
    const float4* cb4 = (const float4*)cb;
    int k0 = w << 7;
    float best = 3.4e38f; int bk = 0;
    #pragma unroll 1
    for (int kk = 0; kk < 128; kk += 4) {
        int ka = k0 + kk;
        float a[4][4] = {};
        #pragma unroll
        for (int q = 0; q < 16; ++q) {
            float f0 = f[q * 4 + 0], f1 = f[q * 4 + 1];
            float f2 = f[q * 4 + 2], f3 = f[q * 4 + 3];
            #pragma unroll
            for (int c = 0; c < 4; ++c) {
                float4 cv = cb4[(ka + c) * 16 + q];
                a[c][0] = fmaf(f0, cv.x, a[c][0]);
                a[c][1] = fmaf(f1, cv.y, a[c][1]);
                a[c][2] = fmaf(f2, cv.z, a[c][2]);
                a[c][3] = fmaf(f3, cv.w, a[c][3]);
            }
        }
        #pragma unroll
        for (int c = 0; c < 4; ++c) {
            float s = fmaf(0.5f, c2[ka + c], -((a[c][0] + a[c][1]) + (a[c][2] + a[c][3])));
            if (s < best) { best = s; bk = ka + c; }
        }
    }
    sS[t] = best; sI[t] = bk;
    __syncthreads();
    if (t < 64) {
        float bs = sS[t]; int bi = sI[t];
        #pragma unroll
        for (int ww = 1; ww < 4; ++ww) {       // ascending k ranges: strict < keeps first min
            float s2 = sS[ww * 64 + t];
            int   i2 = sI[ww * 64 + t];
            if (s2 < bs) { bs = s2; bi = i2; }
        }
        idxOut[blockIdx.x * 64 + t] = bi;
        // loss: sum (cb[bi] - f)^2  (commitment == embedding in fwd)
        float rs = 0.f;
        #pragma unroll
        for (int q = 0; q < 16; ++q) {
            float4 c = cb4[bi * 16 + q];
            float d0 = c.x - f[q * 4 + 0], d1 = c.y - f[q * 4 + 1];
            float d2 = c.z - f[q * 4 + 2], d3 = c.w - f[q * 4 + 3];
            rs = fmaf(d0, d0, rs); rs = fmaf(d1, d1, rs);
            rs = fmaf(d2, d2, rs); rs = fmaf(d3, d3, rs);
        }
        #pragma unroll
        for (int off = 32; off; off >>= 1) rs += __shfl_down(rs, off, 64);
        if (t == 0) atomicAdd(lossAcc, rs);
    }
}

// ---------- decoder conv1 via U-table (co-split 4, 1024 blocks) ----------
__global__ __launch_bounds__(256) void d1_k(const int* __restrict__ idx,
                                            const float* __restrict__ U,
                                            const float* __restrict__ db1,
                                            float* __restrict__ out)
{
    int id = blockIdx.x * 256 + threadIdx.x;          // 262144
    int x = id & 31, y = (id >> 5) & 31;
    int cg = rfl((id >> 10) & 3), n = id >> 12;
    float acc[4];
    #pragma unroll
    for (int j = 0; j < 4; ++j) acc[j] = db1[cg * 4 + j];
    const float4* U4 = (const float4*)U;
    #pragma unroll
    for (int tap = 0; tap < 9; ++tap) {
        int yy = y + tap / 3 - 1, xx = x + tap % 3 - 1;
        if (yy < 0 || yy > 31 || xx < 0 || xx > 31) continue;
        int k = idx[(n << 10) + (yy << 5) + xx];
        float4 u = U4[(k * 9 + tap) * 4 + cg];
        acc[0] += u.x; acc[1] += u.y; acc[2] += u.z; acc[3] += u.w;
    }
    #pragma unroll
    for (int j = 0; j < 4; ++j)
        out[((n * 16 + cg * 4 + j) << 10) + (y << 5) + x] = leakyf(acc[j]);
}

// ---------- ConvT 16->8, K4 S2 P1, parity-block form ----------
__global__ __launch_bounds__(256) void dt2_k(const float* __restrict__ in,
                                             const float* __restrict__ wt,
                                             const float* __restrict__ db2,
                                             float* __restrict__ out)
{
    int id = blockIdx.x * 256 + threadIdx.x;          // 131072
    int x = id & 31, y = (id >> 5) & 31;
    int cg = rfl((id >> 10) & 1), n = id >> 11;
    float acc[2][2][4];
    #pragma unroll
    for (int py = 0; py < 2; ++py)
        #pragma unroll
        for (int px = 0; px < 2; ++px)
            #pragma unroll
            for (int j = 0; j < 4; ++j) acc[py][px][j] = db2[cg * 4 + j];
    const float4* wt4 = (const float4*)wt;
    #pragma unroll
    for (int ci = 0; ci < 16; ++ci) {
        const float* ip = in + ((n * 16 + ci) << 10);
        float v[3][3];
        #pragma unroll
        for (int dy = -1; dy <= 1; ++dy)
            #pragma unroll
            for (int dx = -1; dx <= 1; ++dx) {
                int yy = y + dy, xx = x + dx;
                v[dy + 1][dx + 1] = (yy >= 0 && yy < 32 && xx >= 0 && xx < 32)
                                        ? ip[(yy << 5) + xx] : 0.f;
            }
        #pragma unroll
        for (int ky = 0; ky < 4; ++ky) {
            int py = (ky + 1) & 1;
            int dy = (ky == 0) ? 1 : (ky == 3 ? -1 : 0);
            #pragma unroll
            for (int kx = 0; kx < 4; ++kx) {
                int px = (kx + 1) & 1;
                int dx = (kx == 0) ? 1 : (kx == 3 ? -1 : 0);
                float4 wv = wt4[(cg * 16 + ci) * 16 + ky * 4 + kx];
                float vv = v[dy + 1][dx + 1];
                acc[py][px][0] = fmaf(vv, wv.x, acc[py][px][0]);
                acc[py][px][1] = fmaf(vv, wv.y, acc[py][px][1]);
                acc[py][px][2] = fmaf(vv, wv.z, acc[py][px][2]);
                acc[py][px][3] = fmaf(vv, wv.w, acc[py][px][3]);
            }
        }
    }
    #pragma unroll
    for (int py = 0; py < 2; ++py)
        #pragma unroll
        for (int px = 0; px < 2; ++px)
            #pragma unroll
            for (int j = 0; j < 4; ++j)
                out[((n * 8 + cg * 4 + j) << 12) + ((2 * y + py) << 6) + 2 * x + px] =
                    leakyf(acc[py][px][j]);
}

// ---------- ConvT 8->1, K4 S2 P1, tanh ----------
__global__ __launch_bounds__(256) void dt3_k(const float* __restrict__ in,
                                             const float* __restrict__ dw3,
                                             const float* __restrict__ db3,
                                             float* __restrict__ out)
{
    int id = blockIdx.x * 256 + threadIdx.x;          // 262144
    int x = id & 63, y = (id >> 6) & 63, n = id >> 12;
    float b = db3[0];
    float acc[2][2] = {{b, b}, {b, b}};
    #pragma unroll
    for (int ci = 0; ci < 8; ++ci) {
        const float* ip = in + ((n * 8 + ci) << 12);
        float v[3][3];
        #pragma unroll
        for (int dy = -1; dy <= 1; ++dy)
            #pragma unroll
            for (int dx = -1; dx <= 1; ++dx) {
                int yy = y + dy, xx = x + dx;
                v[dy + 1][dx + 1] = (yy >= 0 && yy < 64 && xx >= 0 && xx < 64)
                                        ? ip[(yy << 6) + xx] : 0.f;
            }
        #pragma unroll
        for (int ky = 0; ky < 4; ++ky) {
            int py = (ky + 1) & 1;
            int dy = (ky == 0) ? 1 : (ky == 3 ? -1 : 0);
            #pragma unroll
            for (int kx = 0; kx < 4; ++kx) {
                int px = (kx + 1) & 1;
                int dx = (kx == 0) ? 1 : (kx == 3 ? -1 : 0);
                acc[py][px] = fmaf(v[dy + 1][dx + 1], dw3[ci * 16 + ky * 4 + kx], acc[py][px]);
            }
        }
    }
    #pragma unroll
    for (int py = 0; py < 2; ++py)
        #pragma unroll
        for (int px = 0; px < 2; ++px)
            out[(n << 14) + ((2 * y + py) << 7) + 2 * x + px] = tanhf(acc[py][px]);
}

__global__ void loss_k(const float* __restrict__ acc, float* __restrict__ out)
{
    out[0] = 1.25f * acc[0] / 4194304.0f;
}

extern "C" void kernel_launch(void* const* d_in, const int* in_sizes, int n_in,
                              void* d_out, int out_size, void* d_ws, size_t ws_size,
                              hipStream_t stream)
{
    const float* x        = (const float*)d_in[0];
    const float* ew1      = (const float*)d_in[1];
    const float* eb1      = (const float*)d_in[2];
    const float* ew2      = (const float*)d_in[3];
    const float* eb2      = (const float*)d_in[4];
    const float* ew3      = (const float*)d_in[5];
    const float* eb3      = (const float*)d_in[6];
    const float* ew4      = (const float*)d_in[7];
    const float* eb4      = (const float*)d_in[8];
    const float* codebook = (const float*)d_in[9];
    const float* dw1      = (const float*)d_in[10];
    const float* db1      = (const float*)d_in[11];
    const float* dw2      = (const float*)d_in[12];
    const float* db2      = (const float*)d_in[13];
    const float* dw3      = (const float*)d_in[14];
    const float* db3      = (const float*)d_in[15];

    float* out = (float*)d_out;
    float* ws  = (float*)d_ws;
    float* A    = ws + OFF_A;
    float* B    = ws + OFF_B;
    float* C    = ws + OFF_C;
    float* D1   = ws + OFF_D1;
    float* D2   = ws + OFF_D2;
    int*   IDX  = (int*)(ws + OFF_IDX);
    float* W1T  = ws + OFF_W1T;
    float* W2T  = ws + OFF_W2T;
    float* W3T  = ws + OFF_W3T;
    float* W4T  = ws + OFF_W4T;
    float* WT2T = ws + OFF_WT2T;
    float* C2   = ws + OFF_C2;
    float* U    = ws + OFF_U;
    float* LOSS = ws + OFF_LOSS;
    float* DWT  = ws + OFF_DWT;

    hipMemsetAsync(LOSS, 0, sizeof(float), stream);
    prep_k<<<68, 256, 0, stream>>>(ew1, ew2, ew3, ew4, dw1, dw2, codebook, ws);
    uprep_k<<<288, 256, 0, stream>>>(DWT, codebook, U);

    e1_k<<<1024, 256, 0, stream>>>(x, W1T, eb1, A);
    e2_k<<<1024, 256, 0, stream>>>(A, W2T, eb2, B);
    e3_k<<<1024, 256, 0, stream>>>(B, W3T, eb3, C);

    vq3_k<<<1024, 256, 0, stream>>>(C, codebook, W4T, C2, eb4, IDX, LOSS);

    d1_k<<<1024, 256, 0, stream>>>(IDX, U, db1, D1);
    dt2_k<<<512, 256, 0, stream>>>(D1, WT2T, db2, D2);
    dt3_k<<<1024, 256, 0, stream>>>(D2, dw3, db3, out);

    loss_k<<<1, 1, 0, stream>>>(LOSS, out + 1048576);
}